// Round 4
// baseline (172.917 us; speedup 1.0000x reference)
//
#include <hip/hip_runtime.h>
#include <hip/hip_bf16.h>

#define DDIM 1024
#define RREG 36
#define TTOK 64
#define KPAD 48    // attn rows padded 36->48, rows [36,48) zero

typedef __attribute__((ext_vector_type(4))) float f32x4;
typedef __attribute__((ext_vector_type(8))) short bf16x8;

__device__ __forceinline__ float sq4(float4 v) {
  return v.x * v.x + v.y * v.y + v.z * v.z + v.w * v.w;
}

__device__ __forceinline__ ushort4 cvt4(float4 v) {
  union { ushort4 u; __hip_bfloat162 h[2]; } r;
  r.h[0] = __float22bfloat162_rn(make_float2(v.x, v.y));
  r.h[1] = __float22bfloat162_rn(make_float2(v.z, v.w));
  return r.u;
}

__device__ __forceinline__ bf16x8 pack8(const float* v) {
  union { bf16x8 x; __hip_bfloat162 h[4]; } u;
#pragma unroll
  for (int i = 0; i < 4; ++i)
    u.h[i] = __float22bfloat162_rn(make_float2(v[2 * i], v[2 * i + 1]));
  return u.x;
}

__device__ __forceinline__ unsigned short f2bf(float x) {
  unsigned int u = __float_as_uint(x);
  u += 0x7fffu + ((u >> 16) & 1u);
  return (unsigned short)(u >> 16);
}

// ---------------- Kernel 1: dots + norms + softmax -> attn^T bf16 ----------------
// grid = B*4 (b, t-tile of 16); block = 256 = 4 waves = 4 K-quarters (K=256 each).
// Each wave stages its own A (cap 16x64) and B (img 48x64) bf16 tiles into
// wave-PRIVATE LDS per 64-float chunk: no __syncthreads in the K-loop, waves
// free-run (the R3 barrier-lockstep was the 50us stall). 2 barriers total.
//
// Per-wave LDS (shorts): A [16][72] = 1152, B [48][72] = 3456 -> 4608 shorts
// (9216 B); x4 waves = 36864 B -> 4 blocks/CU, 16 waves/CU.
// Row stride 72 shorts = 36 dwords == 4 (mod 32): b128 frag reads ~conflict-free.
// After barrier the same LDS is aliased as combine scratch:
//   sdots [4][16][52] f32 (13312 B) + scapn [4][16] (256 B) + simgn [4][48] (768 B)
__global__ __launch_bounds__(256, 4) void scan_attn(
    const float* __restrict__ img, const float* __restrict__ cap,
    unsigned short* __restrict__ attnw) {
  __shared__ __align__(16) unsigned char smem[36864];

  const int tid  = threadIdx.x;
  const int lane = tid & 63;
  const int wave = tid >> 6;        // K-quarter 0..3
  const int fm   = lane & 15;
  const int kq   = lane >> 4;
  const int b    = blockIdx.x >> 2;
  const int t0   = (blockIdx.x & 3) << 4;

  const float* capb = cap + (size_t)b * TTOK * DDIM + (size_t)t0 * DDIM;
  const float* imgb = img + (size_t)b * RREG * DDIM;

  unsigned short* Aw = (unsigned short*)smem + wave * 4608;  // [16][72]
  unsigned short* Bw = Aw + 1152;                            // [48][72]

  // zero B rows 36..47 once (wave-private; in-order DS => visible to our reads)
  {
    unsigned int* bz = (unsigned int*)(Bw + 36 * 72);  // 864 shorts = 432 dwords
    for (int z = lane; z < 432; z += 64) bz[z] = 0u;
  }

  const int ar = lane >> 2;   // A staging: row 0..15
  const int aq = lane & 3;    // A staging: quarter of 64-float window

  float an = 0.f;             // cap-norm^2 partial, row ar
  float bn[9];                // img-norm^2 partials, rows 4i+kq
#pragma unroll
  for (int i = 0; i < 9; ++i) bn[i] = 0.f;

  f32x4 acc0 = {0.f, 0.f, 0.f, 0.f};
  f32x4 acc1 = {0.f, 0.f, 0.f, 0.f};
  f32x4 acc2 = {0.f, 0.f, 0.f, 0.f};

  const int kbase = wave * 256;
#pragma unroll 1
  for (int c = 0; c < 4; ++c) {
    const int koff = kbase + c * 64;
    // -- issue all 13 coalesced float4 loads (16 lines each) --
    float4 avd[4], bvd[9];
#pragma unroll
    for (int i = 0; i < 4; ++i)
      avd[i] = *(const float4*)(capb + ar * DDIM + koff + i * 16 + aq * 4);
#pragma unroll
    for (int i = 0; i < 9; ++i)
      bvd[i] = *(const float4*)(imgb + (4 * i + kq) * DDIM + koff + fm * 4);
    // -- norms + cvt + wave-private LDS writes --
#pragma unroll
    for (int i = 0; i < 4; ++i) {
      an += sq4(avd[i]);
      *(ushort4*)(Aw + ar * 72 + i * 16 + aq * 4) = cvt4(avd[i]);
    }
#pragma unroll
    for (int i = 0; i < 9; ++i) {
      bn[i] += sq4(bvd[i]);
      *(ushort4*)(Bw + (4 * i + kq) * 72 + fm * 4) = cvt4(bvd[i]);
    }
    // our own writes done before our own frag reads (same wave, in-order DS)
    asm volatile("s_waitcnt lgkmcnt(0)" ::: "memory");
    // -- MFMA: A[m=t][k], B[k][n=r]; 2 k-steps x 3 r-tiles --
#pragma unroll
    for (int ks = 0; ks < 2; ++ks) {
      bf16x8 af = *(const bf16x8*)(Aw + fm * 72 + ks * 32 + kq * 8);
      bf16x8 b0 = *(const bf16x8*)(Bw + fm * 72 + ks * 32 + kq * 8);
      bf16x8 b1 = *(const bf16x8*)(Bw + (16 + fm) * 72 + ks * 32 + kq * 8);
      bf16x8 b2 = *(const bf16x8*)(Bw + (32 + fm) * 72 + ks * 32 + kq * 8);
      acc0 = __builtin_amdgcn_mfma_f32_16x16x32_bf16(af, b0, acc0, 0, 0, 0);
      acc1 = __builtin_amdgcn_mfma_f32_16x16x32_bf16(af, b1, acc1, 0, 0, 0);
      acc2 = __builtin_amdgcn_mfma_f32_16x16x32_bf16(af, b2, acc2, 0, 0, 0);
    }
  }

  // reduce norm partials in-register
  an += __shfl_xor(an, 1);
  an += __shfl_xor(an, 2);
#pragma unroll
  for (int i = 0; i < 9; ++i) {
    bn[i] += __shfl_xor(bn[i], 1);
    bn[i] += __shfl_xor(bn[i], 2);
    bn[i] += __shfl_xor(bn[i], 4);
    bn[i] += __shfl_xor(bn[i], 8);
  }

  __syncthreads();   // all staging reads complete; re-purpose LDS as scratch
  float* sdots = (float*)smem;             // [kh][16][52]
  float* scapn = (float*)(smem + 13312);   // [kh][16]
  float* simgn = (float*)(smem + 13568);   // [kh][48]

  if (aq == 0) scapn[wave * 16 + ar] = an;
  if (fm == 0) {
#pragma unroll
    for (int i = 0; i < 9; ++i) simgn[wave * 48 + 4 * i + kq] = bn[i];
  }
  {
    // D layout: row(m=t-local)=kq*4+i, col(n=r-local)=fm
    float* dp = sdots + wave * 832;
#pragma unroll
    for (int i = 0; i < 4; ++i) {
      dp[(kq * 4 + i) * 52 + fm]      = acc0[i];
      dp[(kq * 4 + i) * 52 + 16 + fm] = acc1[i];
      dp[(kq * 4 + i) * 52 + 32 + fm] = acc2[i];
    }
  }
  __syncthreads();

  // ---- combine + softmax: wave 0 only (other waves exit) ----
  if (wave == 0) {
    if (lane < 36) {
      float s = simgn[lane] + simgn[48 + lane] + simgn[96 + lane] + simgn[144 + lane];
      simgn[lane] = sqrtf(s);
    } else if (lane >= 48) {
      int t = lane - 48;
      float s = scapn[t] + scapn[16 + t] + scapn[32 + t] + scapn[48 + t];
      scapn[t] = sqrtf(s);
    }
    // per-lane owner slots: t = lane&15, r = (lane>>4)+4e  (owner-exclusive)
    const int t  = lane & 15;
    const int rb = lane >> 4;
    float nc = scapn[t];
#pragma unroll
    for (int e = 0; e < 9; ++e) {
      int r = rb + 4 * e;
      float d = sdots[t * 52 + r] + sdots[832 + t * 52 + r] +
                sdots[1664 + t * 52 + r] + sdots[2496 + t * 52 + r];
      float dn = fmaxf(simgn[r] * nc, 1e-8f);
      sdots[t * 52 + r] = __fdividef(d, dn);
    }
    if (lane < 16) {
      float sc[RREG];
      float mx = -1e30f;
#pragma unroll
      for (int r = 0; r < RREG; ++r) {
        float v = sdots[lane * 52 + r];
        sc[r] = v;
        mx = fmaxf(mx, v);
      }
      float sum = 0.f;
#pragma unroll
      for (int r = 0; r < RREG; ++r) {
        float ev = __expf(sc[r] - mx);
        sc[r] = ev;
        sum += ev;
      }
      const float rinv = 1.f / sum;
      unsigned short* arow = attnw + ((size_t)b * TTOK + t0 + lane) * KPAD;
#pragma unroll
      for (int r0 = 0; r0 < RREG; r0 += 4) {
        ushort4 p;
        p.x = f2bf(sc[r0 + 0] * rinv);
        p.y = f2bf(sc[r0 + 1] * rinv);
        p.z = f2bf(sc[r0 + 2] * rinv);
        p.w = f2bf(sc[r0 + 3] * rinv);
        *(ushort4*)(arow + r0) = p;
      }
      ushort4 zz; zz.x = 0; zz.y = 0; zz.z = 0; zz.w = 0;
      *(ushort4*)(arow + 36) = zz;
      *(ushort4*)(arow + 40) = zz;
      *(ushort4*)(arow + 44) = zz;
    }
  }
}

// ---------------- Kernel 2: out = attn^T(64x48) . img(48x1024) ----------------
// grid = B*4 (d-chunks of 256), block = 256 (4 waves = 4 t-tiles); no LDS, no
// barriers. ~20us = write floor; unchanged from R3.
__global__ __launch_bounds__(256) void scan_out(
    const float* __restrict__ img, const unsigned short* __restrict__ attnw,
    float* __restrict__ out) {
  const int tid  = threadIdx.x;
  const int lane = tid & 63;
  const int wave = tid >> 6;        // t-tile 0..3
  const int fm   = lane & 15;
  const int kq   = lane >> 4;
  const int b    = blockIdx.x >> 2;
  const int d0   = (blockIdx.x & 3) << 8;

  const float* imgb = img + (size_t)b * RREG * DDIM;
  const unsigned short* attb = attnw + (size_t)b * TTOK * KPAD;
  float* outb = out + (size_t)b * TTOK * DDIM;

  const unsigned short* ap = attb + (wave * 16 + fm) * KPAD;
  bf16x8 zf = {0, 0, 0, 0, 0, 0, 0, 0};
  bf16x8 af0 = *(const bf16x8*)(ap + kq * 8);
  bf16x8 af1 = zf;
  if (kq < 2) af1 = *(const bf16x8*)(ap + 32 + kq * 8);

  for (int s = 0; s < 16; ++s) {
    const int d = d0 + s * 16 + fm;
    float v[8];
#pragma unroll
    for (int j = 0; j < 8; ++j) v[j] = imgb[(kq * 8 + j) * DDIM + d];
    bf16x8 bf0 = pack8(v);
    bf16x8 bf1 = zf;
    if (kq == 0) {
      float w[8];
#pragma unroll
      for (int j = 0; j < 4; ++j) w[j] = imgb[(32 + j) * DDIM + d];
#pragma unroll
      for (int j = 4; j < 8; ++j) w[j] = 0.f;
      bf1 = pack8(w);
    }
    f32x4 o = {0.f, 0.f, 0.f, 0.f};
    o = __builtin_amdgcn_mfma_f32_16x16x32_bf16(af0, bf0, o, 0, 0, 0);
    o = __builtin_amdgcn_mfma_f32_16x16x32_bf16(af1, bf1, o, 0, 0, 0);
    float* op = outb + (wave * 16 + kq * 4) * DDIM + d;
#pragma unroll
    for (int i = 0; i < 4; ++i) op[i * DDIM] = o[i];
  }
}

extern "C" void kernel_launch(void* const* d_in, const int* in_sizes, int n_in,
                              void* d_out, int out_size, void* d_ws, size_t ws_size,
                              hipStream_t stream) {
  const float* img = (const float*)d_in[0];   // (256, 36, 1024) fp32
  const float* cap = (const float*)d_in[1];   // (256, 64, 1024) fp32
  float* out = (float*)d_out;                 // (256, 64, 1024) fp32
  unsigned short* attnw = (unsigned short*)d_ws;  // attn^T bf16 [B][64][48] = 1.5 MB

  scan_attn<<<dim3(1024), dim3(256), 0, stream>>>(img, cap, attnw);
  scan_out<<<dim3(1024), dim3(256), 0, stream>>>(img, attnw, out);
}